// Round 1
// baseline (1987.191 us; speedup 1.0000x reference)
//
#include <hip/hip_runtime.h>
#include <stdint.h>

typedef unsigned short u16;
typedef __attribute__((ext_vector_type(8))) short short8;
typedef __attribute__((ext_vector_type(4))) float floatx4;

// Problem constants
// B=8, NQ=NK=1024, D_MODEL=1024, H=16, D_K=D_V=64

__device__ __forceinline__ u16 f2bf(float f) {
  uint32_t u = __float_as_uint(f);
  u = (u + 0x7fffu + ((u >> 16) & 1u)) >> 16;   // RNE
  return (u16)u;
}

__device__ __forceinline__ void gl_lds16(const void* g, void* l) {
  __builtin_amdgcn_global_load_lds(
      (__attribute__((address_space(1))) void*)g,
      (__attribute__((address_space(3))) void*)l, 16, 0, 0);
}

// ---------------- fp32 -> bf16 conversion (8 elems/thread) ----------------
__global__ __launch_bounds__(256) void cvt_bf16(const float* __restrict__ src,
                                                u16* __restrict__ dst, int n8) {
  int i = blockIdx.x * 256 + threadIdx.x;
  if (i >= n8) return;
  const float4 a = ((const float4*)src)[i * 2];
  const float4 b = ((const float4*)src)[i * 2 + 1];
  short8 o;
  o[0] = (short)f2bf(a.x); o[1] = (short)f2bf(a.y);
  o[2] = (short)f2bf(a.z); o[3] = (short)f2bf(a.w);
  o[4] = (short)f2bf(b.x); o[5] = (short)f2bf(b.y);
  o[6] = (short)f2bf(b.z); o[7] = (short)f2bf(b.w);
  ((short8*)dst)[i] = o;
}

// ---------------- bf16 GEMM: C[M,N] = A[M,K] @ B[N,K]^T + bias ----------------
// m97 structure: 128x128 tile, BK=32, 256 thr (4 waves, each 64x64),
// global_load_lds width-16 staging, mfma_f32_16x16x32_bf16.
// mode 0: out fp32 row-major (out-proj). mode 1: out bf16 permuted (b,h,n,d).
// mode 2: out bf16 permuted-transposed (b,h,d,n)  [for V].
__global__ __launch_bounds__(256) void gemm_bt(
    const u16* __restrict__ A, const u16* __restrict__ Bm,
    const float* __restrict__ bias, float* __restrict__ outF,
    u16* __restrict__ outB, int M, int N, int K, float scale, int mode) {
  __shared__ u16 As[128 * 32];
  __shared__ u16 Bs[128 * 32];
  const int tid = threadIdx.x;
  const int wid = tid >> 6, lane = tid & 63;
  const int lane15 = lane & 15, quad = lane >> 4;
  const int m0 = blockIdx.y * 128, n0 = blockIdx.x * 128;
  const int wm = (wid >> 1) * 64, wn = (wid & 1) * 64;
  const int srow = tid >> 2;          // staging row 0..63
  const int scol = (tid & 3) * 8;     // staging col (elements)

  floatx4 acc[4][4];
#pragma unroll
  for (int i = 0; i < 4; i++)
#pragma unroll
    for (int j = 0; j < 4; j++) acc[i][j] = floatx4{0.f, 0.f, 0.f, 0.f};

  for (int k0 = 0; k0 < K; k0 += 32) {
    __syncthreads();
    gl_lds16(A + (size_t)(m0 + srow) * K + k0 + scol, As + tid * 8);
    gl_lds16(A + (size_t)(m0 + 64 + srow) * K + k0 + scol, As + 2048 + tid * 8);
    gl_lds16(Bm + (size_t)(n0 + srow) * K + k0 + scol, Bs + tid * 8);
    gl_lds16(Bm + (size_t)(n0 + 64 + srow) * K + k0 + scol, Bs + 2048 + tid * 8);
    __syncthreads();   // compiler drains vmcnt(0) before s_barrier

    short8 af[4], bf[4];
#pragma unroll
    for (int i = 0; i < 4; i++)
      af[i] = *(const short8*)(As + (wm + i * 16 + lane15) * 32 + quad * 8);
#pragma unroll
    for (int j = 0; j < 4; j++)
      bf[j] = *(const short8*)(Bs + (wn + j * 16 + lane15) * 32 + quad * 8);
#pragma unroll
    for (int i = 0; i < 4; i++)
#pragma unroll
      for (int j = 0; j < 4; j++)
        acc[i][j] = __builtin_amdgcn_mfma_f32_16x16x32_bf16(af[i], bf[j], acc[i][j], 0, 0, 0);
  }

  // epilogue. C/D layout: col = lane&15, row = quad*4 + r  [m89-verified]
  const int NQ = 1024;
#pragma unroll
  for (int j = 0; j < 4; j++) {
    const int col = n0 + wn + j * 16 + lane15;
    const float bv = bias[col];
#pragma unroll
    for (int i = 0; i < 4; i++) {
      if (mode == 2) {
        // pack 4 consecutive n_ (r=0..3) into one 8B store
        const int rowb = m0 + wm + i * 16 + quad * 4;
        const int b_ = rowb >> 10, n_ = rowb & 1023;
        const int h_ = col >> 6, d_ = col & 63;
        u16 pk[4];
#pragma unroll
        for (int r = 0; r < 4; r++) pk[r] = f2bf((acc[i][j][r] + bv) * scale);
        u16* dp = outB + (((size_t)b_ * 16 + h_) * 64 + d_) * (size_t)NQ + n_;
        *(uint2*)dp = *(const uint2*)pk;
      } else {
#pragma unroll
        for (int r = 0; r < 4; r++) {
          const int row = m0 + wm + i * 16 + quad * 4 + r;
          const float v = (acc[i][j][r] + bv) * scale;
          if (mode == 0) {
            outF[(size_t)row * N + col] = v;
          } else {  // mode 1: (b,h,n,d) bf16
            const int b_ = row >> 10, n_ = row & 1023;
            const int h_ = col >> 6, d_ = col & 63;
            outB[(((size_t)b_ * 16 + h_) * NQ + n_) * 64 + d_] = f2bf(v);
          }
        }
      }
    }
  }
}

// ---------------- fused flash attention ----------------
// grid (B*H, NQ/128); block 256 = 4 waves; wave owns 32 q-rows.
// Qp,Kp: (B*H, 1024, 64) bf16.  Vt: (B*H, 64, 1024) bf16.
// Wgt fp32 / Msk int32: (B*H, 1024, 1024).  AO: (B, 1024, H*64) bf16.
__global__ __launch_bounds__(256) void attn(
    const u16* __restrict__ Qp, const u16* __restrict__ Kp,
    const u16* __restrict__ Vt, const float* __restrict__ Wgt,
    const int* __restrict__ Msk, u16* __restrict__ AO) {
  __shared__ u16 Ps[4][32 * 72];  // per-wave P tile, stride 72 (pad -> 2-way-free banks)
  const int bh = blockIdx.x;
  const int qb = blockIdx.y;
  const int tid = threadIdx.x;
  const int wid = tid >> 6, lane = tid & 63;
  const int lane15 = lane & 15, quad = lane >> 4;
  const int qbase = qb * 128 + wid * 32;

  const u16* Qh = Qp + ((size_t)bh * 1024 + qbase) * 64;
  const u16* Kh = Kp + (size_t)bh * 1024 * 64;
  const u16* Vh = Vt + (size_t)bh * 64 * 1024;
  const size_t wm_base = (size_t)bh * 1024 * 1024;

  // Q fragments, loop-invariant, straight from global (16B contiguous per lane)
  short8 qf[2][2];
#pragma unroll
  for (int mt = 0; mt < 2; mt++)
#pragma unroll
    for (int ks = 0; ks < 2; ks++)
      qf[mt][ks] = *(const short8*)(Qh + (size_t)(mt * 16 + lane15) * 64 + ks * 32 + quad * 8);

  float mrun[2][4], lrun[2][4];
  floatx4 oacc[2][4];
#pragma unroll
  for (int mt = 0; mt < 2; mt++) {
#pragma unroll
    for (int r = 0; r < 4; r++) { mrun[mt][r] = -1e30f; lrun[mt][r] = 0.f; }
#pragma unroll
    for (int nt = 0; nt < 4; nt++) oacc[mt][nt] = floatx4{0.f, 0.f, 0.f, 0.f};
  }

  for (int kc = 0; kc < 1024; kc += 64) {
    __builtin_amdgcn_wave_barrier();  // WAR fence vs previous chunk's Ps reads
    floatx4 sacc[2][4];
#pragma unroll
    for (int mt = 0; mt < 2; mt++)
#pragma unroll
      for (int nt = 0; nt < 4; nt++) sacc[mt][nt] = floatx4{0.f, 0.f, 0.f, 0.f};

    // S = Q K^T (K frags straight from global)
#pragma unroll
    for (int ks = 0; ks < 2; ks++) {
#pragma unroll
      for (int nt = 0; nt < 4; nt++) {
        short8 kf = *(const short8*)(Kh + (size_t)(kc + nt * 16 + lane15) * 64 + ks * 32 + quad * 8);
        sacc[0][nt] = __builtin_amdgcn_mfma_f32_16x16x32_bf16(qf[0][ks], kf, sacc[0][nt], 0, 0, 0);
        sacc[1][nt] = __builtin_amdgcn_mfma_f32_16x16x32_bf16(qf[1][ks], kf, sacc[1][nt], 0, 0, 0);
      }
    }

    // weights, mask, online softmax (per row = quad*4+r within each 16-tile)
#pragma unroll
    for (int mt = 0; mt < 2; mt++)
#pragma unroll
      for (int r = 0; r < 4; r++) {
        const size_t ro = wm_base + (size_t)(qbase + mt * 16 + quad * 4 + r) * 1024 + kc + lane15;
        float sv[4];
#pragma unroll
        for (int nt = 0; nt < 4; nt++) {
          const float w = Wgt[ro + nt * 16];
          const int mk = Msk[ro + nt * 16];
          sv[nt] = mk ? -1e30f : sacc[mt][nt][r] * w;
        }
        float mx = fmaxf(fmaxf(sv[0], sv[1]), fmaxf(sv[2], sv[3]));
        mx = fmaxf(mx, __shfl_xor(mx, 1));
        mx = fmaxf(mx, __shfl_xor(mx, 2));
        mx = fmaxf(mx, __shfl_xor(mx, 4));
        mx = fmaxf(mx, __shfl_xor(mx, 8));
        const float mnew = fmaxf(mrun[mt][r], mx);
        const float alpha = __expf(mrun[mt][r] - mnew);
        mrun[mt][r] = mnew;
        float ps = 0.f;
#pragma unroll
        for (int nt = 0; nt < 4; nt++) {
          const float p = __expf(sv[nt] - mnew);
          ps += p;
          Ps[wid][(mt * 16 + quad * 4 + r) * 72 + nt * 16 + lane15] = f2bf(p);
          oacc[mt][nt][r] *= alpha;
        }
        ps += __shfl_xor(ps, 1);
        ps += __shfl_xor(ps, 2);
        ps += __shfl_xor(ps, 4);
        ps += __shfl_xor(ps, 8);
        lrun[mt][r] = lrun[mt][r] * alpha + ps;
      }

    __builtin_amdgcn_wave_barrier();  // P writes -> A-frag reads (wave-internal, DS in-order)

    // O += P V  (V^T frags straight from global: k=key contiguous)
#pragma unroll
    for (int ks = 0; ks < 2; ks++) {
      short8 pf[2];
#pragma unroll
      for (int mt = 0; mt < 2; mt++)
        pf[mt] = *(const short8*)&Ps[wid][(mt * 16 + lane15) * 72 + ks * 32 + quad * 8];
#pragma unroll
      for (int nt = 0; nt < 4; nt++) {
        short8 vf = *(const short8*)(Vh + (size_t)(nt * 16 + lane15) * 1024 + kc + ks * 32 + quad * 8);
        oacc[0][nt] = __builtin_amdgcn_mfma_f32_16x16x32_bf16(pf[0], vf, oacc[0][nt], 0, 0, 0);
        oacc[1][nt] = __builtin_amdgcn_mfma_f32_16x16x32_bf16(pf[1], vf, oacc[1][nt], 0, 0, 0);
      }
    }
  }

  // epilogue: O / l -> AO (b, q, h*64+d) bf16
  const int b_ = bh >> 4, h_ = bh & 15;
#pragma unroll
  for (int mt = 0; mt < 2; mt++)
#pragma unroll
    for (int r = 0; r < 4; r++) {
      const int row = qbase + mt * 16 + quad * 4 + r;
      const float inv_l = 1.f / lrun[mt][r];
#pragma unroll
      for (int nt = 0; nt < 4; nt++) {
        const int col = nt * 16 + lane15;
        AO[((size_t)b_ * 1024 + row) * 1024 + h_ * 64 + col] = f2bf(oacc[mt][nt][r] * inv_l);
      }
    }
}

extern "C" void kernel_launch(void* const* d_in, const int* in_sizes, int n_in,
                              void* d_out, int out_size, void* d_ws, size_t ws_size,
                              hipStream_t stream) {
  const float* queries = (const float*)d_in[0];
  const float* keys    = (const float*)d_in[1];
  const float* values  = (const float*)d_in[2];
  const int*   mask    = (const int*)d_in[3];
  const float* weights = (const float*)d_in[4];
  const float* Wq = (const float*)d_in[5];
  const float* bq = (const float*)d_in[6];
  const float* Wk = (const float*)d_in[7];
  const float* bk = (const float*)d_in[8];
  const float* Wv = (const float*)d_in[9];
  const float* bv = (const float*)d_in[10];
  const float* Wo = (const float*)d_in[11];
  const float* bo = (const float*)d_in[12];
  float* out = (float*)d_out;

  // workspace layout (120 MB total)
  char* ws = (char*)d_ws;
  const size_t MB = 1024 * 1024;
  u16* qb  = (u16*)(ws + 0 * MB);    // queries bf16   (8192,1024)
  u16* kb  = (u16*)(ws + 16 * MB);
  u16* vb  = (u16*)(ws + 32 * MB);
  u16* wqb = (u16*)(ws + 48 * MB);   // Wq bf16 (1024,1024)
  u16* wkb = (u16*)(ws + 50 * MB);
  u16* wvb = (u16*)(ws + 52 * MB);
  u16* wob = (u16*)(ws + 54 * MB);
  u16* Qp  = (u16*)(ws + 56 * MB);   // (B*H,1024,64) bf16, pre-scaled by 1/8
  u16* Kp  = (u16*)(ws + 72 * MB);   // (B*H,1024,64)
  u16* Vt  = (u16*)(ws + 88 * MB);   // (B*H,64,1024)  transposed for PV B-operand
  u16* AO  = (u16*)(ws + 104 * MB);  // (B,1024,1024) bf16 attention output

  // 1) fp32 -> bf16 converts
  cvt_bf16<<<4096, 256, 0, stream>>>(queries, qb, 8388608 / 8);
  cvt_bf16<<<4096, 256, 0, stream>>>(keys, kb, 8388608 / 8);
  cvt_bf16<<<4096, 256, 0, stream>>>(values, vb, 8388608 / 8);
  cvt_bf16<<<512, 256, 0, stream>>>(Wq, wqb, 1048576 / 8);
  cvt_bf16<<<512, 256, 0, stream>>>(Wk, wkb, 1048576 / 8);
  cvt_bf16<<<512, 256, 0, stream>>>(Wv, wvb, 1048576 / 8);
  cvt_bf16<<<512, 256, 0, stream>>>(Wo, wob, 1048576 / 8);

  // 2) projections (M=8192, N=1024, K=1024)
  dim3 gg(1024 / 128, 8192 / 128);
  gemm_bt<<<gg, 256, 0, stream>>>(qb, wqb, bq, nullptr, Qp, 8192, 1024, 1024, 0.125f, 1);
  gemm_bt<<<gg, 256, 0, stream>>>(kb, wkb, bk, nullptr, Kp, 8192, 1024, 1024, 1.0f, 1);
  gemm_bt<<<gg, 256, 0, stream>>>(vb, wvb, bv, nullptr, Vt, 8192, 1024, 1024, 1.0f, 2);

  // 3) fused masked/weighted softmax attention
  attn<<<dim3(128, 8), 256, 0, stream>>>(Qp, Kp, Vt, weights, mask, AO);

  // 4) output projection -> fp32 d_out
  gemm_bt<<<gg, 256, 0, stream>>>(AO, wob, bo, out, nullptr, 8192, 1024, 1024, 1.0f, 0);
}

// Round 2
// 1455.431 us; speedup vs baseline: 1.3654x; 1.3654x over previous
//
#include <hip/hip_runtime.h>
#include <stdint.h>

typedef unsigned short u16;
typedef __attribute__((ext_vector_type(8))) short short8;
typedef __attribute__((ext_vector_type(4))) float floatx4;
typedef __attribute__((ext_vector_type(4))) int intx4;

// Problem constants: B=8, NQ=NK=1024, D_MODEL=1024, H=16, D_K=D_V=64

__device__ __forceinline__ u16 f2bf(float f) {
  uint32_t u = __float_as_uint(f);
  u = (u + 0x7fffu + ((u >> 16) & 1u)) >> 16;   // RNE
  return (u16)u;
}

__device__ __forceinline__ void gl_lds16(const void* g, void* l) {
  __builtin_amdgcn_global_load_lds(
      (__attribute__((address_space(1))) void*)g,
      (__attribute__((address_space(3))) void*)l, 16, 0, 0);
}

// ---------------- fp32 -> bf16 conversion (8 elems/thread) ----------------
__global__ __launch_bounds__(256) void cvt_bf16(const float* __restrict__ src,
                                                u16* __restrict__ dst, int n8) {
  int i = blockIdx.x * 256 + threadIdx.x;
  if (i >= n8) return;
  const float4 a = ((const float4*)src)[i * 2];
  const float4 b = ((const float4*)src)[i * 2 + 1];
  short8 o;
  o[0] = (short)f2bf(a.x); o[1] = (short)f2bf(a.y);
  o[2] = (short)f2bf(a.z); o[3] = (short)f2bf(a.w);
  o[4] = (short)f2bf(b.x); o[5] = (short)f2bf(b.y);
  o[6] = (short)f2bf(b.z); o[7] = (short)f2bf(b.w);
  ((short8*)dst)[i] = o;
}

// ---------------- bf16 GEMM: C[M,N] = A[M,K] @ B[N,K]^T + bias ----------------
// m97 structure: 128x128 tile, BK=32, 256 thr (4 waves, each 64x64),
// global_load_lds width-16 staging, mfma_f32_16x16x32_bf16.
// mode 0: out fp32 row-major. mode 1: out bf16 (b,h,n,d). mode 2: bf16 (b,h,d,n).
__global__ __launch_bounds__(256) void gemm_bt(
    const u16* __restrict__ A, const u16* __restrict__ Bm,
    const float* __restrict__ bias, float* __restrict__ outF,
    u16* __restrict__ outB, int M, int N, int K, float scale, int mode) {
  __shared__ u16 As[128 * 32];
  __shared__ u16 Bs[128 * 32];
  const int tid = threadIdx.x;
  const int wid = tid >> 6, lane = tid & 63;
  const int lane15 = lane & 15, quad = lane >> 4;
  const int m0 = blockIdx.y * 128, n0 = blockIdx.x * 128;
  const int wm = (wid >> 1) * 64, wn = (wid & 1) * 64;
  const int srow = tid >> 2;
  const int scol = (tid & 3) * 8;

  floatx4 acc[4][4];
#pragma unroll
  for (int i = 0; i < 4; i++)
#pragma unroll
    for (int j = 0; j < 4; j++) acc[i][j] = floatx4{0.f, 0.f, 0.f, 0.f};

  for (int k0 = 0; k0 < K; k0 += 32) {
    __syncthreads();
    gl_lds16(A + (size_t)(m0 + srow) * K + k0 + scol, As + tid * 8);
    gl_lds16(A + (size_t)(m0 + 64 + srow) * K + k0 + scol, As + 2048 + tid * 8);
    gl_lds16(Bm + (size_t)(n0 + srow) * K + k0 + scol, Bs + tid * 8);
    gl_lds16(Bm + (size_t)(n0 + 64 + srow) * K + k0 + scol, Bs + 2048 + tid * 8);
    __syncthreads();

    short8 af[4], bf[4];
#pragma unroll
    for (int i = 0; i < 4; i++)
      af[i] = *(const short8*)(As + (wm + i * 16 + lane15) * 32 + quad * 8);
#pragma unroll
    for (int j = 0; j < 4; j++)
      bf[j] = *(const short8*)(Bs + (wn + j * 16 + lane15) * 32 + quad * 8);
#pragma unroll
    for (int i = 0; i < 4; i++)
#pragma unroll
      for (int j = 0; j < 4; j++)
        acc[i][j] = __builtin_amdgcn_mfma_f32_16x16x32_bf16(af[i], bf[j], acc[i][j], 0, 0, 0);
  }

  const int NQ = 1024;
#pragma unroll
  for (int j = 0; j < 4; j++) {
    const int col = n0 + wn + j * 16 + lane15;
    const float bv = bias[col];
#pragma unroll
    for (int i = 0; i < 4; i++) {
      if (mode == 2) {
        const int rowb = m0 + wm + i * 16 + quad * 4;
        const int b_ = rowb >> 10, n_ = rowb & 1023;
        const int h_ = col >> 6, d_ = col & 63;
        u16 pk[4];
#pragma unroll
        for (int r = 0; r < 4; r++) pk[r] = f2bf((acc[i][j][r] + bv) * scale);
        u16* dp = outB + (((size_t)b_ * 16 + h_) * 64 + d_) * (size_t)NQ + n_;
        *(uint2*)dp = *(const uint2*)pk;
      } else {
#pragma unroll
        for (int r = 0; r < 4; r++) {
          const int row = m0 + wm + i * 16 + quad * 4 + r;
          const float v = (acc[i][j][r] + bv) * scale;
          if (mode == 0) {
            outF[(size_t)row * N + col] = v;
          } else {
            const int b_ = row >> 10, n_ = row & 1023;
            const int h_ = col >> 6, d_ = col & 63;
            outB[(((size_t)b_ * 16 + h_) * NQ + n_) * 64 + d_] = f2bf(v);
          }
        }
      }
    }
  }
}

// ---------------- fused flash attention, S^T formulation ----------------
// grid (B*H, NQ/128); block 256 = 4 waves; wave owns 32 q-rows.
// S^T = K·Q^T so that C-layout reg index r = 4 CONSECUTIVE KEYS at fixed q-row:
// W/M become float4/int4 loads; softmax row reduction = local-16 + shfl_xor(16,32).
__global__ __launch_bounds__(256, 2) void attn(
    const u16* __restrict__ Qp, const u16* __restrict__ Kp,
    const u16* __restrict__ Vt, const float* __restrict__ Wgt,
    const int* __restrict__ Msk, u16* __restrict__ AO) {
  __shared__ u16 Ps[4][32 * 72];
  const int bh = blockIdx.x;
  const int qb = blockIdx.y;
  const int tid = threadIdx.x;
  const int wid = tid >> 6, lane = tid & 63;
  const int lane15 = lane & 15, quad = lane >> 4;
  const int qbase = qb * 128 + wid * 32;

  const u16* Qh = Qp + ((size_t)bh * 1024 + qbase) * 64;
  const u16* Kh = Kp + (size_t)bh * 1024 * 64;
  const u16* Vh = Vt + (size_t)bh * 64 * 1024;
  const float* Wr = Wgt + (size_t)bh * 1024 * 1024 + (size_t)(qbase + lane15) * 1024;
  const int*   Mr = Msk + (size_t)bh * 1024 * 1024 + (size_t)(qbase + lane15) * 1024;

  // Q fragments (B-operand: n=lane15=qrow, k=quad*8+j), loop-invariant
  short8 qf[2][2];
#pragma unroll
  for (int qt = 0; qt < 2; qt++)
#pragma unroll
    for (int ks = 0; ks < 2; ks++)
      qf[qt][ks] = *(const short8*)(Qh + (size_t)(qt * 16 + lane15) * 64 + ks * 32 + quad * 8);

  float mrun[2] = {-1e30f, -1e30f};
  float lrun[2] = {0.f, 0.f};
  floatx4 oacc[2][4];
#pragma unroll
  for (int mt = 0; mt < 2; mt++)
#pragma unroll
    for (int nt = 0; nt < 4; nt++) oacc[mt][nt] = floatx4{0.f, 0.f, 0.f, 0.f};

  for (int kc = 0; kc < 1024; kc += 64) {
    __builtin_amdgcn_wave_barrier();  // WAR vs previous iter's Ps reads

    // phase A: burst-prefetch W (float4) and M (int4) — coalesced 1KB/instr
    floatx4 w4[2][4];
    intx4   m4[2][4];
#pragma unroll
    for (int qt = 0; qt < 2; qt++)
#pragma unroll
      for (int kt = 0; kt < 4; kt++) {
        const int off = qt * 16 * 1024 + kc + kt * 16 + quad * 4;
        w4[qt][kt] = *(const floatx4*)(Wr + off);
        m4[qt][kt] = *(const intx4*)(Mr + off);
      }

    // phase B: S^T = K Q^T.  A=K (m=key), B=Q (n=qrow).
    floatx4 sacc[4][2];
#pragma unroll
    for (int kt = 0; kt < 4; kt++)
#pragma unroll
      for (int qt = 0; qt < 2; qt++) sacc[kt][qt] = floatx4{0.f, 0.f, 0.f, 0.f};
#pragma unroll
    for (int ks = 0; ks < 2; ks++) {
#pragma unroll
      for (int kt = 0; kt < 4; kt++) {
        short8 kf = *(const short8*)(Kh + (size_t)(kc + kt * 16 + lane15) * 64 + ks * 32 + quad * 8);
        sacc[kt][0] = __builtin_amdgcn_mfma_f32_16x16x32_bf16(kf, qf[0][ks], sacc[kt][0], 0, 0, 0);
        sacc[kt][1] = __builtin_amdgcn_mfma_f32_16x16x32_bf16(kf, qf[1][ks], sacc[kt][1], 0, 0, 0);
      }
    }

    // phase C: weights, mask, online softmax.  Lane holds 16 keys of its q-row.
    float alpha[2];
#pragma unroll
    for (int qt = 0; qt < 2; qt++) {
#pragma unroll
      for (int kt = 0; kt < 4; kt++)
#pragma unroll
        for (int r = 0; r < 4; r++)
          sacc[kt][qt][r] = m4[qt][kt][r] ? -1e30f : sacc[kt][qt][r] * w4[qt][kt][r];

      float mx = sacc[0][qt][0];
#pragma unroll
      for (int kt = 0; kt < 4; kt++)
#pragma unroll
        for (int r = 0; r < 4; r++) mx = fmaxf(mx, sacc[kt][qt][r]);
      mx = fmaxf(mx, __shfl_xor(mx, 16));
      mx = fmaxf(mx, __shfl_xor(mx, 32));

      const float mnew = fmaxf(mrun[qt], mx);
      alpha[qt] = __expf(mrun[qt] - mnew);
      mrun[qt] = mnew;

      float ps = 0.f;
#pragma unroll
      for (int kt = 0; kt < 4; kt++) {
        u16 pk[4];
#pragma unroll
        for (int r = 0; r < 4; r++) {
          const float p = __expf(sacc[kt][qt][r] - mnew);
          ps += p;
          pk[r] = f2bf(p);
        }
        const uint32_t lo = (uint32_t)pk[0] | ((uint32_t)pk[1] << 16);
        const uint32_t hi = (uint32_t)pk[2] | ((uint32_t)pk[3] << 16);
        uint2 pv; pv.x = lo; pv.y = hi;
        *(uint2*)&Ps[wid][(qt * 16 + lane15) * 72 + kt * 16 + quad * 4] = pv;
      }
      ps += __shfl_xor(ps, 16);
      ps += __shfl_xor(ps, 32);
      lrun[qt] = lrun[qt] * alpha[qt] + ps;
    }

    __builtin_amdgcn_wave_barrier();  // P writes -> A-frag reads (wave-internal DS in-order)

    // phase D: broadcast alpha into O C-layout rows, rescale O
#pragma unroll
    for (int mt = 0; mt < 2; mt++)
#pragma unroll
      for (int r = 0; r < 4; r++) {
        const float als = __shfl(alpha[mt], quad * 4 + r);
#pragma unroll
        for (int nt = 0; nt < 4; nt++) oacc[mt][nt][r] *= als;
      }

    // phase E: O += P V   (A=P from LDS, B=V^T frags from global)
#pragma unroll
    for (int ks = 0; ks < 2; ks++) {
      short8 pf[2];
#pragma unroll
      for (int mt = 0; mt < 2; mt++)
        pf[mt] = *(const short8*)&Ps[wid][(mt * 16 + lane15) * 72 + ks * 32 + quad * 8];
#pragma unroll
      for (int nt = 0; nt < 4; nt++) {
        short8 vf = *(const short8*)(Vh + (size_t)(nt * 16 + lane15) * 1024 + kc + ks * 32 + quad * 8);
        oacc[0][nt] = __builtin_amdgcn_mfma_f32_16x16x32_bf16(pf[0], vf, oacc[0][nt], 0, 0, 0);
        oacc[1][nt] = __builtin_amdgcn_mfma_f32_16x16x32_bf16(pf[1], vf, oacc[1][nt], 0, 0, 0);
      }
    }
  }

  // epilogue: O / l -> AO (b, q, h*64+d) bf16
  const int b_ = bh >> 4, h_ = bh & 15;
#pragma unroll
  for (int mt = 0; mt < 2; mt++)
#pragma unroll
    for (int r = 0; r < 4; r++) {
      const float ls = __shfl(lrun[mt], quad * 4 + r);
      const float inv_l = 1.f / ls;
      const int row = qbase + mt * 16 + quad * 4 + r;
#pragma unroll
      for (int nt = 0; nt < 4; nt++) {
        const int col = nt * 16 + lane15;
        AO[((size_t)b_ * 1024 + row) * 1024 + h_ * 64 + col] = f2bf(oacc[mt][nt][r] * inv_l);
      }
    }
}

extern "C" void kernel_launch(void* const* d_in, const int* in_sizes, int n_in,
                              void* d_out, int out_size, void* d_ws, size_t ws_size,
                              hipStream_t stream) {
  const float* queries = (const float*)d_in[0];
  const float* keys    = (const float*)d_in[1];
  const float* values  = (const float*)d_in[2];
  const int*   mask    = (const int*)d_in[3];
  const float* weights = (const float*)d_in[4];
  const float* Wq = (const float*)d_in[5];
  const float* bq = (const float*)d_in[6];
  const float* Wk = (const float*)d_in[7];
  const float* bk = (const float*)d_in[8];
  const float* Wv = (const float*)d_in[9];
  const float* bv = (const float*)d_in[10];
  const float* Wo = (const float*)d_in[11];
  const float* bo = (const float*)d_in[12];
  float* out = (float*)d_out;

  char* ws = (char*)d_ws;
  const size_t MB = 1024 * 1024;
  u16* qb  = (u16*)(ws + 0 * MB);
  u16* kb  = (u16*)(ws + 16 * MB);
  u16* vb  = (u16*)(ws + 32 * MB);
  u16* wqb = (u16*)(ws + 48 * MB);
  u16* wkb = (u16*)(ws + 50 * MB);
  u16* wvb = (u16*)(ws + 52 * MB);
  u16* wob = (u16*)(ws + 54 * MB);
  u16* Qp  = (u16*)(ws + 56 * MB);   // (B*H,1024,64) bf16, pre-scaled by 1/8
  u16* Kp  = (u16*)(ws + 72 * MB);   // (B*H,1024,64)
  u16* Vt  = (u16*)(ws + 88 * MB);   // (B*H,64,1024)
  u16* AO  = (u16*)(ws + 104 * MB);  // (B,1024,1024) bf16

  cvt_bf16<<<4096, 256, 0, stream>>>(queries, qb, 8388608 / 8);
  cvt_bf16<<<4096, 256, 0, stream>>>(keys, kb, 8388608 / 8);
  cvt_bf16<<<4096, 256, 0, stream>>>(values, vb, 8388608 / 8);
  cvt_bf16<<<512, 256, 0, stream>>>(Wq, wqb, 1048576 / 8);
  cvt_bf16<<<512, 256, 0, stream>>>(Wk, wkb, 1048576 / 8);
  cvt_bf16<<<512, 256, 0, stream>>>(Wv, wvb, 1048576 / 8);
  cvt_bf16<<<512, 256, 0, stream>>>(Wo, wob, 1048576 / 8);

  dim3 gg(1024 / 128, 8192 / 128);
  gemm_bt<<<gg, 256, 0, stream>>>(qb, wqb, bq, nullptr, Qp, 8192, 1024, 1024, 0.125f, 1);
  gemm_bt<<<gg, 256, 0, stream>>>(kb, wkb, bk, nullptr, Kp, 8192, 1024, 1024, 1.0f, 1);
  gemm_bt<<<gg, 256, 0, stream>>>(vb, wvb, bv, nullptr, Vt, 8192, 1024, 1024, 1.0f, 2);

  attn<<<dim3(128, 8), 256, 0, stream>>>(Qp, Kp, Vt, weights, mask, AO);

  gemm_bt<<<gg, 256, 0, stream>>>(AO, wob, bo, out, nullptr, 8192, 1024, 1024, 1.0f, 0);
}